// Round 5
// baseline (109.699 us; speedup 1.0000x reference)
//
#include <hip/hip_runtime.h>

// B=8, Cin=64, H=W=128, Cout=64, 9 bilinear taps at (i+0.4, j+0.4) == exact 4x4
// conv with zero pad. Implicit GEMM, bf16 MFMA 16x16x32.
//
// v8: max-TLP restructure (tile/traffic identical to v7).
//   - v7 post-mortem: conv ~17 us vs 11.7 us traffic floor; 4 waves/SIMD
//     can't hide ~900cy HBM latency across stage<->compute phases.
//   - v8: 256 thr = 4 waves/block, wave = 64 px x 16 Cout (acc[4], 16 VGPR).
//     8 blocks/CU x 4 waves = 32 waves/CU = 8/SIMD (hardware max).
//     __launch_bounds__(256,8) caps VGPR at 64 (est. ~60 used).
//   - stage: wave stages its own channel chunk (= wave id, uniform SGPR base),
//     4 row-items/wave; same XOR slot swizzle, halo via +4096 (same phase).
//   - epilogue: direct f32x4 stores from acc (D-layout: lane writes 4
//     contiguous f32 at px=mi*16+q*4, row o=wave*16+m15); LDS transpose and
//     2 barriers deleted. 64B/row segments write-combine in L2.
//   - T5 s_setprio(1) around MFMA cluster (32 waves/CU are phase-diverse).
//   - same (p, rs, 32ch-MFMA) accumulation order -> bitwise-identical output.

#define CIN   64
#define COUT  64
#define HH    128
#define WW    128
#define NC    68    // tile cols: col c <-> global x = x0 - 1 + c, c in [0,66]

typedef __attribute__((ext_vector_type(8))) short bf16x8;   // 8 bf16 = 4 VGPRs
typedef __attribute__((ext_vector_type(4))) float f32x4;
typedef __attribute__((ext_vector_type(4))) unsigned int u32x4;

__device__ __forceinline__ unsigned short f2bf(float f) {
  unsigned int u = __float_as_uint(f);
  u = (u + 0x7fffu + ((u >> 16) & 1u)) >> 16;   // RNE
  return (unsigned short)u;
}

__device__ __forceinline__ unsigned int cvtpk(float lo, float hi) {
  unsigned int r;                                // D = {bf16(lo), bf16(hi)} RNE
  asm("v_cvt_pk_bf16_f32 %0, %1, %2" : "=v"(r) : "v"(lo), "v"(hi));
  return r;
}

// ---------------------------------------------------------------------------
// W4[o][c][r][s] = sum_k w[o,c,k] * cy_k(r-iy_k) * cx_k(s-ix_k).
// Stream layout: wb2[(((p*16+rs)*4 + n)*64 + lane)*8 + j]; consuming lane l
// holds o = n*16 + (l&15), ch = p*32 + (l>>4)*8 + j, for tap rs. (verified)
// ---------------------------------------------------------------------------
__global__ void make_wb(const float* __restrict__ wgt,
                        const float* __restrict__ off,
                        unsigned short* __restrict__ wb2)
{
  int id = blockIdx.x * 64 + threadIdx.x;       // 4096 = 64*64
  int o = id >> 6, c = id & 63;
  float W16[16];
  #pragma unroll
  for (int i = 0; i < 16; ++i) W16[i] = 0.f;
  for (int k = 0; k < 9; ++k) {
    float dy = off[2*k], dx = off[2*k+1];
    float fyf = floorf(dy), fxf = floorf(dx);
    int   iy = (int)fyf,   ix = (int)fxf;       // in {0,1,2}
    float fy = dy - fyf,   fx = dx - fxf;
    float wk = wgt[(o*CIN + c)*9 + k];
    W16[(iy  )*4 + ix  ] += wk * (1.f-fy)*(1.f-fx);
    W16[(iy  )*4 + ix+1] += wk * (1.f-fy)*fx;
    W16[(iy+1)*4 + ix  ] += wk * fy*(1.f-fx);
    W16[(iy+1)*4 + ix+1] += wk * fy*fx;
  }
  int p = c >> 5, q = (c >> 3) & 3, j = c & 7;
  int n = o >> 4, m15 = o & 15;
  int lanei = q*16 + m15;
  for (int rs = 0; rs < 16; ++rs)
    wb2[(size_t)(((p*16 + rs)*4 + n)*64 + lanei)*8 + j] = f2bf(W16[rs]);
}

// ---------------------------------------------------------------------------
// conv: WG = 256 threads (4 waves), tile = 1 out row x 64 px x 64 Cout.
// Wave = 64 px x 16 Cout (wave index = Cout quarter = staged channel chunk).
// LDS: 4 rows x 68 cols x 32 ch bf16, XOR slot swizzle. 17408 B -> 8 blk/CU.
// ---------------------------------------------------------------------------
__global__ __launch_bounds__(256, 8)   // 8 waves/EU -> 8 blocks/CU, 32 waves/CU
void conv_mfma(const float* __restrict__ x,
               const unsigned short* __restrict__ wb2,
               float* __restrict__ out)
{
  __shared__ __align__(16) unsigned short tile[4 * NC * 32]; // 17408 B

  const int wg  = blockIdx.x;                   // 2048
  const int xcd = wg & 7;
  const int i   = wg >> 3;                      // 0..255
  const int b   = i >> 5;                       // 0..7
  const int r5  = i & 31;
  const int y0  = xcd * 16 + (r5 >> 1);         // XCD-local 16-row band
  const int x0  = (r5 & 1) * 64;                // x half
  const int t    = threadIdx.x;
  const int wave = t >> 6;                      // 0..3: Cout quarter & chunk
  const int lane = t & 63;
  const int m15  = lane & 15;
  const int q    = lane >> 4;
  const int wv   = __builtin_amdgcn_readfirstlane(wave);

  // ---- per-lane staging constants ----
  int gx   = x0 - 1 + lane;
  bool gxv = ((unsigned)gx < (unsigned)WW);
  int gxc  = gx < 0 ? 0 : (gx > WW-1 ? WW-1 : gx);
  int gxh  = x0 + 63 + lane;                    // halo cols 64..66 (lanes 0..2)
  bool gxhv = ((unsigned)gxh < (unsigned)WW);
  int gxhc = gxh < 0 ? 0 : (gxh > WW-1 ? WW-1 : gxh);

  // LDS store base: cell(row,col,slot) at row*4352 + col*64 + slot*16 bytes,
  // slot = (chunk + (col>>2)) & 3, chunk == wv (wave-uniform).
  // Halo col = 64+lane has the same slot phase -> main address + 4096.
  const int w4 = (lane >> 2) & 3;
  char* pst = (char*)tile + lane*64 + ((wv + w4) & 3)*16;

  // A-fragment read pointers: c = mi*16 + m15 + s; slot phase invariant under
  // mi*16 -> aptr[s] + r*4352 + mi*1024 (all-immediate offsets in the rs loop).
  const char* aptr[4];
  #pragma unroll
  for (int s = 0; s < 4; ++s) {
    int c0   = m15 + s;
    int slot = (q + (c0 >> 2)) & 3;
    aptr[s] = (const char*)tile + c0*64 + slot*16;
  }

  f32x4 acc[4];
  #pragma unroll
  for (int mi = 0; mi < 4; ++mi)
    acc[mi] = (f32x4){0.f, 0.f, 0.f, 0.f};

  #pragma unroll
  for (int p = 0; p < 2; ++p) {                 // channel pass: c in [32p, 32p+32)
    if (p) __syncthreads();                     // pass-0 tile reads complete

    // ---- stage: 4 row-items/wave, chunk = wv (8 ch) ----
    #pragma unroll
    for (int it = 0; it < 4; ++it) {
      const int gy = y0 + it - 1;               // uniform, -1..129
      char* dst = pst + it*4352;
      if ((unsigned)gy < (unsigned)HH) {        // scalar branch
        const float* ps = x + ((size_t)((b*CIN + p*32 + wv*8)*HH + gy))*WW;
        float v[8];
        #pragma unroll
        for (int cc = 0; cc < 8; ++cc) v[cc] = ps[(size_t)cc*HH*WW + gxc];
        unsigned int pk[4];
        #pragma unroll
        for (int ii = 0; ii < 4; ++ii) {
          pk[ii] = cvtpk(v[2*ii], v[2*ii+1]);
          pk[ii] = gxv ? pk[ii] : 0u;           // zero-pad col gx==-1/128/129
        }
        *(u32x4*)dst = *(u32x4*)pk;
        if (lane < 3) {                         // halo cols 64..66
          float vh[8];
          #pragma unroll
          for (int cc = 0; cc < 8; ++cc) vh[cc] = ps[(size_t)cc*HH*WW + gxhc];
          unsigned int ph[4];
          #pragma unroll
          for (int ii = 0; ii < 4; ++ii) {
            ph[ii] = cvtpk(vh[2*ii], vh[2*ii+1]);
            ph[ii] = gxhv ? ph[ii] : 0u;
          }
          *(u32x4*)(dst + 4096) = *(u32x4*)ph;
        }
      } else if (p == 0) {                      // OOB row: zero once; pass 1 keeps it
        *(u32x4*)dst = (u32x4){0u,0u,0u,0u};
        if (lane < 3) *(u32x4*)(dst + 4096) = (u32x4){0u,0u,0u,0u};
      }
    }
    __syncthreads();

    // ---- compute: 16 rs steps; B = stream load (n = wave), A = imm-offset LDS ----
    const char* wp = (const char*)wb2 + (size_t)p*65536 + wv*1024 + (size_t)lane*16;
    __builtin_amdgcn_s_setprio(1);
    #pragma unroll
    for (int rs = 0; rs < 16; ++rs) {
      const int r = rs >> 2, s = rs & 3;
      bf16x8 bfr = *(const bf16x8*)(wp + rs*4096);
      bf16x8 afr[4];
      #pragma unroll
      for (int mi = 0; mi < 4; ++mi)
        afr[mi] = *(const bf16x8*)(aptr[s] + r*4352 + mi*1024);
      #pragma unroll
      for (int mi = 0; mi < 4; ++mi)
        acc[mi] = __builtin_amdgcn_mfma_f32_16x16x32_bf16(afr[mi], bfr, acc[mi], 0, 0, 0);
    }
    __builtin_amdgcn_s_setprio(0);
  }

  // ---- epilogue: direct stores. lane (m15,q), reg j -> o = wave*16+m15,
  //      px = mi*16 + q*4 + j (4 contiguous f32 per store). ----
  const int o = wave*16 + m15;
  float* orow = out + (((size_t)(b*COUT + o))*HH + y0)*WW + x0 + q*4;
  #pragma unroll
  for (int mi = 0; mi < 4; ++mi)
    *(f32x4*)&orow[mi*16] = acc[mi];
}

// ---------------------------------------------------------------------------
extern "C" void kernel_launch(void* const* d_in, const int* in_sizes, int n_in,
                              void* d_out, int out_size, void* d_ws, size_t ws_size,
                              hipStream_t stream)
{
  const float* x   = (const float*)d_in[0];   // [8,64,128,128] fp32
  const float* wgt = (const float*)d_in[1];   // [64,64,9] fp32
  const float* off = (const float*)d_in[2];   // [9,2] fp32
  float* out = (float*)d_out;                 // [8,64,128,128] fp32
  unsigned short* wb2 = (unsigned short*)d_ws;// 128 KB stream-layout weights

  make_wb<<<64, 64, 0, stream>>>(wgt, off, wb2);
  conv_mfma<<<2048, 256, 0, stream>>>(x, wb2, out);
}